// Round 11
// baseline (485.119 us; speedup 1.0000x reference)
//
#include <hip/hip_runtime.h>
#include <hip/hip_bf16.h>
#include <math.h>

#define N_ENVS   4096
#define N_AGENTS 64
#define OBS_DIM  256
#define HIDDEN   512
#define HEADK    32
#define BROWS    128   // rows per block = 64 envs x 2 agents

typedef __attribute__((ext_vector_type(8))) short bf16x8;
typedef __attribute__((ext_vector_type(4))) float f32x4;

// HW packed f32x2 -> bf16x2 (RNE). One VALU op replaces ~8 for two elements.
static __device__ __forceinline__ unsigned cvt_pk_bf16(float lo, float hi) {
    unsigned r;
    asm("v_cvt_pk_bf16_f32 %0, %1, %2" : "=v"(r) : "v"(lo), "v"(hi));
    return r;
}

static __device__ __forceinline__ unsigned short f2bf(float x) {
    union { float f; unsigned int u; } v; v.f = x;
    unsigned int r = (v.u + 0x7FFFu + ((v.u >> 16) & 1u)) >> 16;
    return (unsigned short)r;
}

// Convert + transpose weights to bf16, N-major (so B-fragments are 16B contiguous).
__global__ void prep_weights_kernel(const float* __restrict__ W1,
                                    const float* __restrict__ W2,
                                    const float* __restrict__ HW1,
                                    unsigned short* __restrict__ W1T,
                                    unsigned short* __restrict__ W2T,
                                    unsigned short* __restrict__ HW1T) {
    int id = blockIdx.x * 256 + threadIdx.x;
    if (id < 131072) {                      // W1 [256][512] -> W1T [512][256]
        int k = id >> 9, n = id & 511;
        W1T[n * 256 + k] = f2bf(W1[id]);
    } else if (id < 131072 + 262144) {      // W2 [512][512] -> W2T [512][512]
        int t = id - 131072;
        int k = t >> 9, n = t & 511;
        W2T[n * 512 + k] = f2bf(W2[t]);
    } else if (id < 131072 + 262144 + 1048576) {  // HW1 [64][512][32] -> HW1T [64][32][512]
        int t = id - (131072 + 262144);
        int ag = t >> 14;
        int rem = t & 16383;
        int hh = rem >> 5, c = rem & 31;
        HW1T[((ag << 5) + c) * 512 + hh] = f2bf(HW1[t]);
    }
}

// Fused MLP. Block = 128 rows (64 envs x 2 agents), 1024 thr = 16 waves.
// Round-11 change: wave tiles 128x32 -> 64x64 (2 row-groups x 8 col-groups).
// Same acc budget (4x4 frags = 64 regs) but each A-fragment feeds 4 MFMAs
// instead of 2 -> A-tile LDS reads halve (3328 -> 1792 b128/block); LDS was
// the dominant pipe at round 10. Cost: 2x weight reads from L2 (~1.6MB/block,
// well under L2 BW). B prefetch dropped (bnxt was +16 arch regs -> spill risk
// at the 64-arch-reg budget); per-step L2 latency hides under 4-wave/SIMD TLP.
// Operand-swapped MFMA (transposed C frags) + cvt_pk epilogues kept from r10.
__launch_bounds__(1024, 1)
__global__ void fused_mlp_kernel(const float* __restrict__ obs,
                                 const float* __restrict__ b1,
                                 const float* __restrict__ b2,
                                 const float* __restrict__ Hb1,
                                 const float* __restrict__ HW2,
                                 const float* __restrict__ Hb2,
                                 const unsigned short* __restrict__ W1T,
                                 const unsigned short* __restrict__ W2T,
                                 const unsigned short* __restrict__ HW1T,
                                 float* __restrict__ out) {
    __shared__ unsigned short buf[BROWS * 512];  // 128 KB: obs(first half), h, feat
    __shared__ float gpart[BROWS * 36];          // 18 KB : g (pad 36)

    const int tid  = threadIdx.x;
    const int lane = tid & 63;
    const int wid  = tid >> 6;   // 0..15
    const int wr   = wid >> 3;   // 0..1 : row group (64 rows)
    const int wc   = wid & 7;    // 0..7 : col group (64 cols)
    const int l15  = lane & 15;
    const int lk   = lane >> 4;  // 0..3
    const int e0   = blockIdx.x * 64;
    const int ap   = blockIdx.y; // agent pair: agents 2ap, 2ap+1

    const f32x4 fzero = {0.f, 0.f, 0.f, 0.f};

    // ------------- stage obs tile [128][256] bf16 swizzled; row = j*64 + e -------------
    {
        const unsigned fbase = ((unsigned)e0 * 64u + 2u * (unsigned)ap) * 256u;
        #pragma unroll 1
        for (int g = 0; g < 4; ++g) {
            unsigned gi  = (unsigned)tid + 1024u * g;   // 4096 groups of 8 floats
            unsigned row = gi >> 5;                     // 0..127
            unsigned kg  = (gi & 31u) << 3;
            unsigned fidx = fbase + (row & 63u) * 16384u + (row >> 6) * 256u + kg;
            const float4* p = reinterpret_cast<const float4*>(obs + fidx);
            float4 v0 = p[0], v1 = p[1];
            uint4 w;
            w.x = cvt_pk_bf16(v0.x, v0.y);
            w.y = cvt_pk_bf16(v0.z, v0.w);
            w.z = cvt_pk_bf16(v1.x, v1.y);
            w.w = cvt_pk_bf16(v1.z, v1.w);
            unsigned byt = (row * 512u + kg * 2u) ^ ((row & 7u) << 4);
            *reinterpret_cast<uint4*>(&buf[byt >> 1]) = w;
        }
    }
    __syncthreads();

    // ---------------- GEMM1: h = relu(obs @ W1 + b1), K=256 ----------------
    f32x4 acc[4][4];   // [mi][ni]: thread = act-row wr*64+mi*16+l15, cols wc*64+ni*16+lk*4..+3
    #pragma unroll
    for (int i = 0; i < 4; ++i)
        #pragma unroll
        for (int j = 0; j < 4; ++j) acc[i][j] = fzero;

    {
        const unsigned short* bbase = W1T + (size_t)(wc * 64 + l15) * 256 + lk * 8;
        #pragma unroll 1
        for (int ks = 0; ks < 8; ++ks) {
            const int kk = ks * 32 + lk * 8;
            bf16x8 bcur[4];
            #pragma unroll
            for (int ni = 0; ni < 4; ++ni)
                bcur[ni] = *reinterpret_cast<const bf16x8*>(bbase + ni * 16 * 256 + ks * 32);
            #pragma unroll
            for (int mi = 0; mi < 4; ++mi) {
                int row = wr * 64 + mi * 16 + l15;
                bf16x8 af = *reinterpret_cast<const bf16x8*>(&buf[((row * 512 + kk * 2) ^ ((row & 7) << 4)) >> 1]);
                #pragma unroll
                for (int ni = 0; ni < 4; ++ni)
                    acc[mi][ni] = __builtin_amdgcn_mfma_f32_16x16x32_bf16(bcur[ni], af, acc[mi][ni], 0, 0, 0);
            }
        }
    }
    __syncthreads();   // all obs reads done -> safe to overwrite buf with h

    // epilogue: +b1, relu, packed b64 writes into buf ([128][512] swizzled)
    #pragma unroll
    for (int ni = 0; ni < 4; ++ni) {
        const int col0 = wc * 64 + ni * 16 + lk * 4;
        const float4 bias = *reinterpret_cast<const float4*>(b1 + col0);
        #pragma unroll
        for (int mi = 0; mi < 4; ++mi) {
            int row = wr * 64 + mi * 16 + l15;
            float v0 = fmaxf(acc[mi][ni][0] + bias.x, 0.f);
            float v1 = fmaxf(acc[mi][ni][1] + bias.y, 0.f);
            float v2 = fmaxf(acc[mi][ni][2] + bias.z, 0.f);
            float v3 = fmaxf(acc[mi][ni][3] + bias.w, 0.f);
            uint2 w = { cvt_pk_bf16(v0, v1), cvt_pk_bf16(v2, v3) };
            int byt = (row * 1024 + col0 * 2) ^ ((row & 7) << 4);
            *reinterpret_cast<uint2*>(&buf[byt >> 1]) = w;
        }
    }
    __syncthreads();

    // ---------------- GEMM2: feat = relu(h @ W2 + b2), K=512 ----------------
    #pragma unroll
    for (int i = 0; i < 4; ++i)
        #pragma unroll
        for (int j = 0; j < 4; ++j) acc[i][j] = fzero;

    {
        const unsigned short* bbase = W2T + (size_t)(wc * 64 + l15) * 512 + lk * 8;
        #pragma unroll 1
        for (int ks = 0; ks < 16; ++ks) {
            const int kk = ks * 32 + lk * 8;
            bf16x8 bcur[4];
            #pragma unroll
            for (int ni = 0; ni < 4; ++ni)
                bcur[ni] = *reinterpret_cast<const bf16x8*>(bbase + ni * 16 * 512 + ks * 32);
            #pragma unroll
            for (int mi = 0; mi < 4; ++mi) {
                int row = wr * 64 + mi * 16 + l15;
                bf16x8 af = *reinterpret_cast<const bf16x8*>(&buf[((row * 1024 + kk * 2) ^ ((row & 7) << 4)) >> 1]);
                #pragma unroll
                for (int ni = 0; ni < 4; ++ni)
                    acc[mi][ni] = __builtin_amdgcn_mfma_f32_16x16x32_bf16(bcur[ni], af, acc[mi][ni], 0, 0, 0);
            }
        }
    }
    __syncthreads();   // all h reads done -> safe to overwrite buf with feat

    // epilogue: +b2, relu, packed b64 writes into buf ([128][512] swizzled)
    #pragma unroll
    for (int ni = 0; ni < 4; ++ni) {
        const int col0 = wc * 64 + ni * 16 + lk * 4;
        const float4 bias = *reinterpret_cast<const float4*>(b2 + col0);
        #pragma unroll
        for (int mi = 0; mi < 4; ++mi) {
            int row = wr * 64 + mi * 16 + l15;
            float v0 = fmaxf(acc[mi][ni][0] + bias.x, 0.f);
            float v1 = fmaxf(acc[mi][ni][1] + bias.y, 0.f);
            float v2 = fmaxf(acc[mi][ni][2] + bias.z, 0.f);
            float v3 = fmaxf(acc[mi][ni][3] + bias.w, 0.f);
            uint2 w = { cvt_pk_bf16(v0, v1), cvt_pk_bf16(v2, v3) };
            int byt = (row * 1024 + col0 * 2) ^ ((row & 7) << 4);
            *reinterpret_cast<uint2*>(&buf[byt >> 1]) = w;
        }
    }
    __syncthreads();

    // ---------------- head1: g = relu(feat @ HW1[agent] + Hb1), N=32 ----------------
    // 16 waves: per agent of the pair, 4 row-quarters x 2 col-halves, full K=512.
    {
        const int ja  = wid >> 3;             // agent within pair
        const int sub = wid & 7;
        const int hm  = sub >> 1;             // row quarter 0..3
        const int hc  = sub & 1;              // col half 0..1
        const int a32 = ((2 * ap + ja) << 5);
        const unsigned short* hbase = HW1T + (size_t)(a32 + hc * 16 + l15) * 512 + lk * 8;
        f32x4 hacc = fzero;
        bf16x8 hb = *reinterpret_cast<const bf16x8*>(hbase);
        #pragma unroll 1
        for (int ks = 0; ks < 16; ++ks) {
            const int kn = (ks < 15 ? ks + 1 : 15);
            bf16x8 hn = *reinterpret_cast<const bf16x8*>(hbase + kn * 32);
            const int kk = ks * 32 + lk * 8;
            int row = ja * 64 + hm * 16 + l15;
            int byt = (row * 1024 + kk * 2) ^ ((row & 7) << 4);
            bf16x8 afh = *reinterpret_cast<const bf16x8*>(&buf[byt >> 1]);
            hacc = __builtin_amdgcn_mfma_f32_16x16x32_bf16(hb, afh, hacc, 0, 0, 0);
            hb = hn;
        }
        // transposed frag: thread owns feat-row ja*64+hm*16+l15, cols hc*16+lk*4+0..3
        const int col0 = hc * 16 + lk * 4;
        const float4 hbias = *reinterpret_cast<const float4*>(Hb1 + a32 + col0);
        int row = ja * 64 + hm * 16 + l15;
        float4 g;
        g.x = fmaxf(hacc[0] + hbias.x, 0.f);
        g.y = fmaxf(hacc[1] + hbias.y, 0.f);
        g.z = fmaxf(hacc[2] + hbias.z, 0.f);
        g.w = fmaxf(hacc[3] + hbias.w, 0.f);
        *reinterpret_cast<float4*>(&gpart[row * 36 + col0]) = g;
    }
    __syncthreads();

    // ---------------- head2: out = sigmoid(g . HW2[agent] + Hb2) ----------------
    if (tid < BROWS) {
        int e = tid & 63, j = tid >> 6;
        int a = 2 * ap + j;
        float x = Hb2[a];
        #pragma unroll 2
        for (int k = 0; k < 32; ++k)
            x += gpart[tid * 36 + k] * HW2[(a << 5) + k];
        out[(size_t)(e0 + e) * N_AGENTS + a] = 1.f / (1.f + expf(-x));
    }
}

extern "C" void kernel_launch(void* const* d_in, const int* in_sizes, int n_in,
                              void* d_out, int out_size, void* d_ws, size_t ws_size,
                              hipStream_t stream) {
    const float* obs = (const float*)d_in[0];
    const float* W1  = (const float*)d_in[1];
    const float* b1  = (const float*)d_in[2];
    const float* W2  = (const float*)d_in[3];
    const float* b2  = (const float*)d_in[4];
    const float* HW1 = (const float*)d_in[5];
    const float* Hb1 = (const float*)d_in[6];
    const float* HW2 = (const float*)d_in[7];
    const float* Hb2 = (const float*)d_in[8];
    float* out = (float*)d_out;

    unsigned short* W1T  = (unsigned short*)d_ws;     // 131072 elems
    unsigned short* W2T  = W1T + 131072;              // 262144 elems
    unsigned short* HW1T = W2T + 262144;              // 1048576 elems

    prep_weights_kernel<<<5632, 256, 0, stream>>>(W1, W2, HW1, W1T, W2T, HW1T);

    dim3 grid(N_ENVS / 64, N_AGENTS / 2);
    fused_mlp_kernel<<<grid, 1024, 0, stream>>>(obs, b1, b2, Hb1, HW2, Hb2,
                                                W1T, W2T, HW1T, out);
}

// Round 12
// 483.376 us; speedup vs baseline: 1.0036x; 1.0036x over previous
//
#include <hip/hip_runtime.h>
#include <hip/hip_bf16.h>
#include <math.h>

#define N_ENVS   4096
#define N_AGENTS 64
#define OBS_DIM  256
#define HIDDEN   512
#define HEADK    32
#define BROWS    128   // rows per block = 64 envs x 2 agents

typedef __attribute__((ext_vector_type(8))) short bf16x8;
typedef __attribute__((ext_vector_type(4))) float f32x4;

// HW packed f32x2 -> bf16x2 (RNE). One VALU op replaces ~8 for two elements.
static __device__ __forceinline__ unsigned cvt_pk_bf16(float lo, float hi) {
    unsigned r;
    asm("v_cvt_pk_bf16_f32 %0, %1, %2" : "=v"(r) : "v"(lo), "v"(hi));
    return r;
}

static __device__ __forceinline__ unsigned short f2bf(float x) {
    union { float f; unsigned int u; } v; v.f = x;
    unsigned int r = (v.u + 0x7FFFu + ((v.u >> 16) & 1u)) >> 16;
    return (unsigned short)r;
}

// Convert + transpose weights to bf16, N-major (so B-fragments are 16B contiguous).
__global__ void prep_weights_kernel(const float* __restrict__ W1,
                                    const float* __restrict__ W2,
                                    const float* __restrict__ HW1,
                                    unsigned short* __restrict__ W1T,
                                    unsigned short* __restrict__ W2T,
                                    unsigned short* __restrict__ HW1T) {
    int id = blockIdx.x * 256 + threadIdx.x;
    if (id < 131072) {                      // W1 [256][512] -> W1T [512][256]
        int k = id >> 9, n = id & 511;
        W1T[n * 256 + k] = f2bf(W1[id]);
    } else if (id < 131072 + 262144) {      // W2 [512][512] -> W2T [512][512]
        int t = id - 131072;
        int k = t >> 9, n = t & 511;
        W2T[n * 512 + k] = f2bf(W2[t]);
    } else if (id < 131072 + 262144 + 1048576) {  // HW1 [64][512][32] -> HW1T [64][32][512]
        int t = id - (131072 + 262144);
        int ag = t >> 14;
        int rem = t & 16383;
        int hh = rem >> 5, c = rem & 31;
        HW1T[((ag << 5) + c) * 512 + hh] = f2bf(HW1[t]);
    }
}

// Fused MLP. Block = 128 rows (64 envs x 2 agents), 1024 thr = 16 waves,
// wave tile 64x64 (2 row-groups x 8 col-groups, acc[4][4]=64 AGPR-side regs).
// Round-10 vs 11 isolation: depth-1 B prefetch is worth ~160us (L2 latency
// exposure per K-step without it: ~300cy vs ~310cy of 4-wave MFMA cover —
// lockstep waves stall together); 64x64 tiling independently halves A-LDS
// reads (conflicts 3.16e7 -> 1.9e7). This round combines both.
// Arch budget: bcur 16 + bnxt 16 + af 8 + addr ~15 = 55 < 64 (acc on AGPRs).
// WRITE_SIZE is the spill sentinel.
__launch_bounds__(1024, 1)
__global__ void fused_mlp_kernel(const float* __restrict__ obs,
                                 const float* __restrict__ b1,
                                 const float* __restrict__ b2,
                                 const float* __restrict__ Hb1,
                                 const float* __restrict__ HW2,
                                 const float* __restrict__ Hb2,
                                 const unsigned short* __restrict__ W1T,
                                 const unsigned short* __restrict__ W2T,
                                 const unsigned short* __restrict__ HW1T,
                                 float* __restrict__ out) {
    __shared__ unsigned short buf[BROWS * 512];  // 128 KB: obs(first half), h, feat
    __shared__ float gpart[BROWS * 36];          // 18 KB : g (pad 36)

    const int tid  = threadIdx.x;
    const int lane = tid & 63;
    const int wid  = tid >> 6;   // 0..15
    const int wr   = wid >> 3;   // 0..1 : row group (64 rows)
    const int wc   = wid & 7;    // 0..7 : col group (64 cols)
    const int l15  = lane & 15;
    const int lk   = lane >> 4;  // 0..3
    const int e0   = blockIdx.x * 64;
    const int ap   = blockIdx.y; // agent pair: agents 2ap, 2ap+1

    const f32x4 fzero = {0.f, 0.f, 0.f, 0.f};

    // ------------- stage obs tile [128][256] bf16 swizzled; row = j*64 + e -------------
    {
        const unsigned fbase = ((unsigned)e0 * 64u + 2u * (unsigned)ap) * 256u;
        #pragma unroll 1
        for (int g = 0; g < 4; ++g) {
            unsigned gi  = (unsigned)tid + 1024u * g;   // 4096 groups of 8 floats
            unsigned row = gi >> 5;                     // 0..127
            unsigned kg  = (gi & 31u) << 3;
            unsigned fidx = fbase + (row & 63u) * 16384u + (row >> 6) * 256u + kg;
            const float4* p = reinterpret_cast<const float4*>(obs + fidx);
            float4 v0 = p[0], v1 = p[1];
            uint4 w;
            w.x = cvt_pk_bf16(v0.x, v0.y);
            w.y = cvt_pk_bf16(v0.z, v0.w);
            w.z = cvt_pk_bf16(v1.x, v1.y);
            w.w = cvt_pk_bf16(v1.z, v1.w);
            unsigned byt = (row * 512u + kg * 2u) ^ ((row & 7u) << 4);
            *reinterpret_cast<uint4*>(&buf[byt >> 1]) = w;
        }
    }
    __syncthreads();

    // ---------------- GEMM1: h = relu(obs @ W1 + b1), K=256 ----------------
    f32x4 acc[4][4];   // [mi][ni]: thread = act-row wr*64+mi*16+l15, cols wc*64+ni*16+lk*4..+3
    #pragma unroll
    for (int i = 0; i < 4; ++i)
        #pragma unroll
        for (int j = 0; j < 4; ++j) acc[i][j] = fzero;

    {
        const unsigned short* bbase = W1T + (size_t)(wc * 64 + l15) * 256 + lk * 8;
        bf16x8 bcur[4];
        #pragma unroll
        for (int ni = 0; ni < 4; ++ni)
            bcur[ni] = *reinterpret_cast<const bf16x8*>(bbase + ni * 16 * 256);
        #pragma unroll 1
        for (int ks = 0; ks < 8; ++ks) {
            bf16x8 bnxt[4];
            const int kn = (ks < 7 ? ks + 1 : 7);
            #pragma unroll
            for (int ni = 0; ni < 4; ++ni)
                bnxt[ni] = *reinterpret_cast<const bf16x8*>(bbase + ni * 16 * 256 + kn * 32);
            const int kk = ks * 32 + lk * 8;
            #pragma unroll
            for (int mi = 0; mi < 4; ++mi) {
                int row = wr * 64 + mi * 16 + l15;
                bf16x8 af = *reinterpret_cast<const bf16x8*>(&buf[((row * 512 + kk * 2) ^ ((row & 7) << 4)) >> 1]);
                #pragma unroll
                for (int ni = 0; ni < 4; ++ni)
                    acc[mi][ni] = __builtin_amdgcn_mfma_f32_16x16x32_bf16(bcur[ni], af, acc[mi][ni], 0, 0, 0);
            }
            #pragma unroll
            for (int ni = 0; ni < 4; ++ni) bcur[ni] = bnxt[ni];
        }
    }
    __syncthreads();   // all obs reads done -> safe to overwrite buf with h

    // epilogue: +b1, relu, packed b64 writes into buf ([128][512] swizzled)
    #pragma unroll
    for (int ni = 0; ni < 4; ++ni) {
        const int col0 = wc * 64 + ni * 16 + lk * 4;
        const float4 bias = *reinterpret_cast<const float4*>(b1 + col0);
        #pragma unroll
        for (int mi = 0; mi < 4; ++mi) {
            int row = wr * 64 + mi * 16 + l15;
            float v0 = fmaxf(acc[mi][ni][0] + bias.x, 0.f);
            float v1 = fmaxf(acc[mi][ni][1] + bias.y, 0.f);
            float v2 = fmaxf(acc[mi][ni][2] + bias.z, 0.f);
            float v3 = fmaxf(acc[mi][ni][3] + bias.w, 0.f);
            uint2 w = { cvt_pk_bf16(v0, v1), cvt_pk_bf16(v2, v3) };
            int byt = (row * 1024 + col0 * 2) ^ ((row & 7) << 4);
            *reinterpret_cast<uint2*>(&buf[byt >> 1]) = w;
        }
    }
    __syncthreads();

    // ---------------- GEMM2: feat = relu(h @ W2 + b2), K=512 ----------------
    #pragma unroll
    for (int i = 0; i < 4; ++i)
        #pragma unroll
        for (int j = 0; j < 4; ++j) acc[i][j] = fzero;

    {
        const unsigned short* bbase = W2T + (size_t)(wc * 64 + l15) * 512 + lk * 8;
        bf16x8 bcur[4];
        #pragma unroll
        for (int ni = 0; ni < 4; ++ni)
            bcur[ni] = *reinterpret_cast<const bf16x8*>(bbase + ni * 16 * 512);
        #pragma unroll 1
        for (int ks = 0; ks < 16; ++ks) {
            bf16x8 bnxt[4];
            const int kn = (ks < 15 ? ks + 1 : 15);
            #pragma unroll
            for (int ni = 0; ni < 4; ++ni)
                bnxt[ni] = *reinterpret_cast<const bf16x8*>(bbase + ni * 16 * 512 + kn * 32);
            const int kk = ks * 32 + lk * 8;
            #pragma unroll
            for (int mi = 0; mi < 4; ++mi) {
                int row = wr * 64 + mi * 16 + l15;
                bf16x8 af = *reinterpret_cast<const bf16x8*>(&buf[((row * 1024 + kk * 2) ^ ((row & 7) << 4)) >> 1]);
                #pragma unroll
                for (int ni = 0; ni < 4; ++ni)
                    acc[mi][ni] = __builtin_amdgcn_mfma_f32_16x16x32_bf16(bcur[ni], af, acc[mi][ni], 0, 0, 0);
            }
            #pragma unroll
            for (int ni = 0; ni < 4; ++ni) bcur[ni] = bnxt[ni];
        }
    }
    __syncthreads();   // all h reads done -> safe to overwrite buf with feat

    // epilogue: +b2, relu, packed b64 writes into buf ([128][512] swizzled)
    #pragma unroll
    for (int ni = 0; ni < 4; ++ni) {
        const int col0 = wc * 64 + ni * 16 + lk * 4;
        const float4 bias = *reinterpret_cast<const float4*>(b2 + col0);
        #pragma unroll
        for (int mi = 0; mi < 4; ++mi) {
            int row = wr * 64 + mi * 16 + l15;
            float v0 = fmaxf(acc[mi][ni][0] + bias.x, 0.f);
            float v1 = fmaxf(acc[mi][ni][1] + bias.y, 0.f);
            float v2 = fmaxf(acc[mi][ni][2] + bias.z, 0.f);
            float v3 = fmaxf(acc[mi][ni][3] + bias.w, 0.f);
            uint2 w = { cvt_pk_bf16(v0, v1), cvt_pk_bf16(v2, v3) };
            int byt = (row * 1024 + col0 * 2) ^ ((row & 7) << 4);
            *reinterpret_cast<uint2*>(&buf[byt >> 1]) = w;
        }
    }
    __syncthreads();

    // ---------------- head1: g = relu(feat @ HW1[agent] + Hb1), N=32 ----------------
    // 16 waves: per agent of the pair, 4 row-quarters x 2 col-halves, full K=512.
    {
        const int ja  = wid >> 3;             // agent within pair
        const int sub = wid & 7;
        const int hm  = sub >> 1;             // row quarter 0..3
        const int hc  = sub & 1;              // col half 0..1
        const int a32 = ((2 * ap + ja) << 5);
        const unsigned short* hbase = HW1T + (size_t)(a32 + hc * 16 + l15) * 512 + lk * 8;
        f32x4 hacc = fzero;
        bf16x8 hb = *reinterpret_cast<const bf16x8*>(hbase);
        #pragma unroll 1
        for (int ks = 0; ks < 16; ++ks) {
            const int kn = (ks < 15 ? ks + 1 : 15);
            bf16x8 hn = *reinterpret_cast<const bf16x8*>(hbase + kn * 32);
            const int kk = ks * 32 + lk * 8;
            int row = ja * 64 + hm * 16 + l15;
            int byt = (row * 1024 + kk * 2) ^ ((row & 7) << 4);
            bf16x8 afh = *reinterpret_cast<const bf16x8*>(&buf[byt >> 1]);
            hacc = __builtin_amdgcn_mfma_f32_16x16x32_bf16(hb, afh, hacc, 0, 0, 0);
            hb = hn;
        }
        // transposed frag: thread owns feat-row ja*64+hm*16+l15, cols hc*16+lk*4+0..3
        const int col0 = hc * 16 + lk * 4;
        const float4 hbias = *reinterpret_cast<const float4*>(Hb1 + a32 + col0);
        int row = ja * 64 + hm * 16 + l15;
        float4 g;
        g.x = fmaxf(hacc[0] + hbias.x, 0.f);
        g.y = fmaxf(hacc[1] + hbias.y, 0.f);
        g.z = fmaxf(hacc[2] + hbias.z, 0.f);
        g.w = fmaxf(hacc[3] + hbias.w, 0.f);
        *reinterpret_cast<float4*>(&gpart[row * 36 + col0]) = g;
    }
    __syncthreads();

    // ---------------- head2: out = sigmoid(g . HW2[agent] + Hb2) ----------------
    if (tid < BROWS) {
        int e = tid & 63, j = tid >> 6;
        int a = 2 * ap + j;
        float x = Hb2[a];
        #pragma unroll 2
        for (int k = 0; k < 32; ++k)
            x += gpart[tid * 36 + k] * HW2[(a << 5) + k];
        out[(size_t)(e0 + e) * N_AGENTS + a] = 1.f / (1.f + expf(-x));
    }
}

extern "C" void kernel_launch(void* const* d_in, const int* in_sizes, int n_in,
                              void* d_out, int out_size, void* d_ws, size_t ws_size,
                              hipStream_t stream) {
    const float* obs = (const float*)d_in[0];
    const float* W1  = (const float*)d_in[1];
    const float* b1  = (const float*)d_in[2];
    const float* W2  = (const float*)d_in[3];
    const float* b2  = (const float*)d_in[4];
    const float* HW1 = (const float*)d_in[5];
    const float* Hb1 = (const float*)d_in[6];
    const float* HW2 = (const float*)d_in[7];
    const float* Hb2 = (const float*)d_in[8];
    float* out = (float*)d_out;

    unsigned short* W1T  = (unsigned short*)d_ws;     // 131072 elems
    unsigned short* W2T  = W1T + 131072;              // 262144 elems
    unsigned short* HW1T = W2T + 262144;              // 1048576 elems

    prep_weights_kernel<<<5632, 256, 0, stream>>>(W1, W2, HW1, W1T, W2T, HW1T);

    dim3 grid(N_ENVS / 64, N_AGENTS / 2);
    fused_mlp_kernel<<<grid, 1024, 0, stream>>>(obs, b1, b2, Hb1, HW2, Hb2,
                                                W1T, W2T, HW1T, out);
}

// Round 13
// 445.138 us; speedup vs baseline: 1.0898x; 1.0859x over previous
//
#include <hip/hip_runtime.h>
#include <hip/hip_bf16.h>
#include <math.h>

#define N_ENVS   4096
#define N_AGENTS 64
#define OBS_DIM  256
#define HIDDEN   512
#define HEADK    32
#define BE       64    // rows per block = 64 envs x 1 agent

typedef __attribute__((ext_vector_type(8))) short bf16x8;
typedef __attribute__((ext_vector_type(4))) float f32x4;

// HW packed f32x2 -> bf16x2 (RNE).
static __device__ __forceinline__ unsigned cvt_pk_bf16(float lo, float hi) {
    unsigned r;
    asm("v_cvt_pk_bf16_f32 %0, %1, %2" : "=v"(r) : "v"(lo), "v"(hi));
    return r;
}

static __device__ __forceinline__ unsigned short f2bf(float x) {
    union { float f; unsigned int u; } v; v.f = x;
    unsigned int r = (v.u + 0x7FFFu + ((v.u >> 16) & 1u)) >> 16;
    return (unsigned short)r;
}

// Convert + transpose weights to bf16, N-major (so B-fragments are 16B contiguous).
__global__ void prep_weights_kernel(const float* __restrict__ W1,
                                    const float* __restrict__ W2,
                                    const float* __restrict__ HW1,
                                    unsigned short* __restrict__ W1T,
                                    unsigned short* __restrict__ W2T,
                                    unsigned short* __restrict__ HW1T) {
    int id = blockIdx.x * 256 + threadIdx.x;
    if (id < 131072) {                      // W1 [256][512] -> W1T [512][256]
        int k = id >> 9, n = id & 511;
        W1T[n * 256 + k] = f2bf(W1[id]);
    } else if (id < 131072 + 262144) {      // W2 [512][512] -> W2T [512][512]
        int t = id - 131072;
        int k = t >> 9, n = t & 511;
        W2T[n * 512 + k] = f2bf(W2[t]);
    } else if (id < 131072 + 262144 + 1048576) {  // HW1 [64][512][32] -> HW1T [64][32][512]
        int t = id - (131072 + 262144);
        int ag = t >> 14;
        int rem = t & 16383;
        int hh = rem >> 5, c = rem & 31;
        HW1T[((ag << 5) + c) * 512 + hh] = f2bf(HW1[t]);
    }
}

// Fused MLP. Round-13 structure: block = 64 rows (64 envs x 1 agent),
// 512 thr = 8 waves, wave tile 64x64 (acc[4][4] = 64 AGPR-side regs).
// LDS = 64KB buf + 9KB gpart = 73KB -> TWO blocks/CU co-resident: the two
// blocks' serial phases (stage/GEMM/epilogue/head, 7 barriers) interleave,
// hiding the ~60% phase-serialization stall measured at r10 (1 block/CU,
// pipes all <24% busy). Square 64x64 tile is safe here: ONE row-group =>
// every weight fragment still fetched exactly once per block (r12's 2x B-dup
// regression came from 2 row-groups, not the tile shape).
// Reg budget at cap 128 (launch_bounds 512,4): acc 64 + bcur 16 + bnxt 16 +
// af 4 + addr ~15 = ~115 -- same mix r12 ran spill-free at cap 128.
// WRITE_SIZE is the spill sentinel.
__launch_bounds__(512, 4)
__global__ void fused_mlp_kernel(const float* __restrict__ obs,
                                 const float* __restrict__ b1,
                                 const float* __restrict__ b2,
                                 const float* __restrict__ Hb1,
                                 const float* __restrict__ HW2,
                                 const float* __restrict__ Hb2,
                                 const unsigned short* __restrict__ W1T,
                                 const unsigned short* __restrict__ W2T,
                                 const unsigned short* __restrict__ HW1T,
                                 float* __restrict__ out) {
    __shared__ unsigned short buf[BE * 512];   // 64 KB: obs(first half), h, feat
    __shared__ float gpart[BE * 36];           // 9 KB : g (pad 36)

    const int tid  = threadIdx.x;
    const int lane = tid & 63;
    const int wid  = tid >> 6;   // 0..7 : col group (64 cols each)
    const int l15  = lane & 15;
    const int lk   = lane >> 4;  // 0..3
    const int e0   = blockIdx.x * BE;
    const int ag   = blockIdx.y;

    const f32x4 fzero = {0.f, 0.f, 0.f, 0.f};

    // ------------- stage obs tile [64][256] bf16 swizzled -------------
    {
        const unsigned fbase = ((unsigned)e0 * 64u + (unsigned)ag) * 256u;
        #pragma unroll 1
        for (int g = 0; g < 4; ++g) {
            unsigned gi  = (unsigned)tid + 512u * g;    // 2048 groups of 8 floats
            unsigned row = gi >> 5;                     // 0..63
            unsigned kg  = (gi & 31u) << 3;
            unsigned fidx = fbase + row * 16384u + kg;
            const float4* p = reinterpret_cast<const float4*>(obs + fidx);
            float4 v0 = p[0], v1 = p[1];
            uint4 w;
            w.x = cvt_pk_bf16(v0.x, v0.y);
            w.y = cvt_pk_bf16(v0.z, v0.w);
            w.z = cvt_pk_bf16(v1.x, v1.y);
            w.w = cvt_pk_bf16(v1.z, v1.w);
            unsigned byt = (row * 512u + kg * 2u) ^ ((row & 7u) << 4);
            *reinterpret_cast<uint4*>(&buf[byt >> 1]) = w;
        }
    }
    __syncthreads();

    // ---------------- GEMM1: h = relu(obs @ W1 + b1), K=256 ----------------
    f32x4 acc[4][4];   // [mi][ni]: thread = act-row mi*16+l15, cols wid*64+ni*16+lk*4..+3
    #pragma unroll
    for (int i = 0; i < 4; ++i)
        #pragma unroll
        for (int j = 0; j < 4; ++j) acc[i][j] = fzero;

    {
        const unsigned short* bbase = W1T + (size_t)(wid * 64 + l15) * 256 + lk * 8;
        bf16x8 bcur[4];
        #pragma unroll
        for (int ni = 0; ni < 4; ++ni)
            bcur[ni] = *reinterpret_cast<const bf16x8*>(bbase + ni * 16 * 256);
        #pragma unroll 1
        for (int ks = 0; ks < 8; ++ks) {
            bf16x8 bnxt[4];
            const int kn = (ks < 7 ? ks + 1 : 7);
            #pragma unroll
            for (int ni = 0; ni < 4; ++ni)
                bnxt[ni] = *reinterpret_cast<const bf16x8*>(bbase + ni * 16 * 256 + kn * 32);
            const int kk = ks * 32 + lk * 8;
            #pragma unroll
            for (int mi = 0; mi < 4; ++mi) {
                int row = mi * 16 + l15;
                bf16x8 af = *reinterpret_cast<const bf16x8*>(&buf[((row * 512 + kk * 2) ^ ((row & 7) << 4)) >> 1]);
                #pragma unroll
                for (int ni = 0; ni < 4; ++ni)
                    acc[mi][ni] = __builtin_amdgcn_mfma_f32_16x16x32_bf16(bcur[ni], af, acc[mi][ni], 0, 0, 0);
            }
            #pragma unroll
            for (int ni = 0; ni < 4; ++ni) bcur[ni] = bnxt[ni];
        }
    }
    __syncthreads();   // all obs reads done -> safe to overwrite buf with h

    // epilogue: +b1, relu, packed b64 writes into buf ([64][512] swizzled)
    #pragma unroll
    for (int ni = 0; ni < 4; ++ni) {
        const int col0 = wid * 64 + ni * 16 + lk * 4;
        const float4 bias = *reinterpret_cast<const float4*>(b1 + col0);
        #pragma unroll
        for (int mi = 0; mi < 4; ++mi) {
            int row = mi * 16 + l15;
            float v0 = fmaxf(acc[mi][ni][0] + bias.x, 0.f);
            float v1 = fmaxf(acc[mi][ni][1] + bias.y, 0.f);
            float v2 = fmaxf(acc[mi][ni][2] + bias.z, 0.f);
            float v3 = fmaxf(acc[mi][ni][3] + bias.w, 0.f);
            uint2 w = { cvt_pk_bf16(v0, v1), cvt_pk_bf16(v2, v3) };
            int byt = (row * 1024 + col0 * 2) ^ ((row & 7) << 4);
            *reinterpret_cast<uint2*>(&buf[byt >> 1]) = w;
        }
    }
    __syncthreads();

    // ---------------- GEMM2: feat = relu(h @ W2 + b2), K=512 ----------------
    #pragma unroll
    for (int i = 0; i < 4; ++i)
        #pragma unroll
        for (int j = 0; j < 4; ++j) acc[i][j] = fzero;

    {
        const unsigned short* bbase = W2T + (size_t)(wid * 64 + l15) * 512 + lk * 8;
        bf16x8 bcur[4];
        #pragma unroll
        for (int ni = 0; ni < 4; ++ni)
            bcur[ni] = *reinterpret_cast<const bf16x8*>(bbase + ni * 16 * 512);
        #pragma unroll 1
        for (int ks = 0; ks < 16; ++ks) {
            bf16x8 bnxt[4];
            const int kn = (ks < 15 ? ks + 1 : 15);
            #pragma unroll
            for (int ni = 0; ni < 4; ++ni)
                bnxt[ni] = *reinterpret_cast<const bf16x8*>(bbase + ni * 16 * 512 + kn * 32);
            const int kk = ks * 32 + lk * 8;
            #pragma unroll
            for (int mi = 0; mi < 4; ++mi) {
                int row = mi * 16 + l15;
                bf16x8 af = *reinterpret_cast<const bf16x8*>(&buf[((row * 1024 + kk * 2) ^ ((row & 7) << 4)) >> 1]);
                #pragma unroll
                for (int ni = 0; ni < 4; ++ni)
                    acc[mi][ni] = __builtin_amdgcn_mfma_f32_16x16x32_bf16(bcur[ni], af, acc[mi][ni], 0, 0, 0);
            }
            #pragma unroll
            for (int ni = 0; ni < 4; ++ni) bcur[ni] = bnxt[ni];
        }
    }
    __syncthreads();   // all h reads done -> safe to overwrite buf with feat

    // epilogue: +b2, relu, packed b64 writes into buf ([64][512] swizzled)
    #pragma unroll
    for (int ni = 0; ni < 4; ++ni) {
        const int col0 = wid * 64 + ni * 16 + lk * 4;
        const float4 bias = *reinterpret_cast<const float4*>(b2 + col0);
        #pragma unroll
        for (int mi = 0; mi < 4; ++mi) {
            int row = mi * 16 + l15;
            float v0 = fmaxf(acc[mi][ni][0] + bias.x, 0.f);
            float v1 = fmaxf(acc[mi][ni][1] + bias.y, 0.f);
            float v2 = fmaxf(acc[mi][ni][2] + bias.z, 0.f);
            float v3 = fmaxf(acc[mi][ni][3] + bias.w, 0.f);
            uint2 w = { cvt_pk_bf16(v0, v1), cvt_pk_bf16(v2, v3) };
            int byt = (row * 1024 + col0 * 2) ^ ((row & 7) << 4);
            *reinterpret_cast<uint2*>(&buf[byt >> 1]) = w;
        }
    }
    __syncthreads();

    // ---------------- head1: g = relu(feat @ HW1[ag] + Hb1[ag]), N=32 ----------------
    // 8 waves: 4 row-quarters x 2 col-halves, full K=512.
    {
        const int hm  = wid >> 1;             // row quarter 0..3
        const int hc  = wid & 1;              // col half 0..1
        const int a32 = (ag << 5);
        const unsigned short* hbase = HW1T + (size_t)(a32 + hc * 16 + l15) * 512 + lk * 8;
        f32x4 hacc = fzero;
        bf16x8 hb = *reinterpret_cast<const bf16x8*>(hbase);
        #pragma unroll 1
        for (int ks = 0; ks < 16; ++ks) {
            const int kn = (ks < 15 ? ks + 1 : 15);
            bf16x8 hn = *reinterpret_cast<const bf16x8*>(hbase + kn * 32);
            const int kk = ks * 32 + lk * 8;
            int row = hm * 16 + l15;
            int byt = (row * 1024 + kk * 2) ^ ((row & 7) << 4);
            bf16x8 afh = *reinterpret_cast<const bf16x8*>(&buf[byt >> 1]);
            hacc = __builtin_amdgcn_mfma_f32_16x16x32_bf16(hb, afh, hacc, 0, 0, 0);
            hb = hn;
        }
        // transposed frag: thread owns feat-row hm*16+l15, cols hc*16+lk*4+0..3
        const int col0 = hc * 16 + lk * 4;
        const float4 hbias = *reinterpret_cast<const float4*>(Hb1 + a32 + col0);
        int row = hm * 16 + l15;
        float4 g;
        g.x = fmaxf(hacc[0] + hbias.x, 0.f);
        g.y = fmaxf(hacc[1] + hbias.y, 0.f);
        g.z = fmaxf(hacc[2] + hbias.z, 0.f);
        g.w = fmaxf(hacc[3] + hbias.w, 0.f);
        *reinterpret_cast<float4*>(&gpart[row * 36 + col0]) = g;
    }
    __syncthreads();

    // ---------------- head2: out = sigmoid(g . HW2[ag] + Hb2[ag]) ----------------
    if (tid < BE) {
        float x = Hb2[ag];
        #pragma unroll 2
        for (int k = 0; k < 32; ++k)
            x += gpart[tid * 36 + k] * HW2[(ag << 5) + k];
        out[(size_t)(e0 + tid) * N_AGENTS + ag] = 1.f / (1.f + expf(-x));
    }
}

extern "C" void kernel_launch(void* const* d_in, const int* in_sizes, int n_in,
                              void* d_out, int out_size, void* d_ws, size_t ws_size,
                              hipStream_t stream) {
    const float* obs = (const float*)d_in[0];
    const float* W1  = (const float*)d_in[1];
    const float* b1  = (const float*)d_in[2];
    const float* W2  = (const float*)d_in[3];
    const float* b2  = (const float*)d_in[4];
    const float* HW1 = (const float*)d_in[5];
    const float* Hb1 = (const float*)d_in[6];
    const float* HW2 = (const float*)d_in[7];
    const float* Hb2 = (const float*)d_in[8];
    float* out = (float*)d_out;

    unsigned short* W1T  = (unsigned short*)d_ws;     // 131072 elems
    unsigned short* W2T  = W1T + 131072;              // 262144 elems
    unsigned short* HW1T = W2T + 262144;              // 1048576 elems

    prep_weights_kernel<<<5632, 256, 0, stream>>>(W1, W2, HW1, W1T, W2T, HW1T);

    dim3 grid(N_ENVS / BE, N_AGENTS);
    fused_mlp_kernel<<<grid, 512, 0, stream>>>(obs, b1, b2, Hb1, HW2, Hb2,
                                               W1T, W2T, HW1T, out);
}

// Round 14
// 441.988 us; speedup vs baseline: 1.0976x; 1.0071x over previous
//
#include <hip/hip_runtime.h>
#include <hip/hip_bf16.h>
#include <math.h>

#define N_ENVS   4096
#define N_AGENTS 64
#define OBS_DIM  256
#define HIDDEN   512
#define HEADK    32
#define BE       64    // rows per block = 64 envs x 1 agent

typedef __attribute__((ext_vector_type(8))) short bf16x8;
typedef __attribute__((ext_vector_type(4))) float f32x4;

// HW packed f32x2 -> bf16x2 (RNE).
static __device__ __forceinline__ unsigned cvt_pk_bf16(float lo, float hi) {
    unsigned r;
    asm("v_cvt_pk_bf16_f32 %0, %1, %2" : "=v"(r) : "v"(lo), "v"(hi));
    return r;
}

static __device__ __forceinline__ unsigned short f2bf(float x) {
    union { float f; unsigned int u; } v; v.f = x;
    unsigned int r = (v.u + 0x7FFFu + ((v.u >> 16) & 1u)) >> 16;
    return (unsigned short)r;
}

// Convert + transpose weights to bf16, N-major (so B-fragments are 16B contiguous).
__global__ void prep_weights_kernel(const float* __restrict__ W1,
                                    const float* __restrict__ W2,
                                    const float* __restrict__ HW1,
                                    unsigned short* __restrict__ W1T,
                                    unsigned short* __restrict__ W2T,
                                    unsigned short* __restrict__ HW1T) {
    int id = blockIdx.x * 256 + threadIdx.x;
    if (id < 131072) {                      // W1 [256][512] -> W1T [512][256]
        int k = id >> 9, n = id & 511;
        W1T[n * 256 + k] = f2bf(W1[id]);
    } else if (id < 131072 + 262144) {      // W2 [512][512] -> W2T [512][512]
        int t = id - 131072;
        int k = t >> 9, n = t & 511;
        W2T[n * 512 + k] = f2bf(W2[t]);
    } else if (id < 131072 + 262144 + 1048576) {  // HW1 [64][512][32] -> HW1T [64][32][512]
        int t = id - (131072 + 262144);
        int ag = t >> 14;
        int rem = t & 16383;
        int hh = rem >> 5, c = rem & 31;
        HW1T[((ag << 5) + c) * 512 + hh] = f2bf(HW1[t]);
    }
}

// Fused MLP, round-14: the 100%-occupancy configuration.
// Block = 64 rows (64 envs x 1 agent), 1024 thr = 16 waves, wave tile
// 64 rows x 32 cols -> acc[4][2] = 32 AGPR-side regs. launch_bounds(1024,8)
// caps at 64 TOTAL regs/wave -> 8 waves/SIMD, and LDS 73KB -> 2 blocks/CU:
// 32 waves/CU (100%). NO explicit B-prefetch (bnxt won't fit in the 32
// remaining arch regs): the bet is 8-wave TLP covers L2 (~300cy) + LDS
// (~120cy) latency -- per-SIMD per K-step there are 64 MFMAs (~1240cy) of
// cover vs 4-wave r11 where lockstep exposure regressed 485us.
// Per-wave K-step: 2 global B loads (each reused 4x -- r10's proven ratio)
// + 4 swizzled A ds_read_b128 + 8 MFMAs.
// WRITE_SIZE is the spill sentinel; OccupancyPercent is the thesis sentinel.
__launch_bounds__(1024, 8)
__global__ void fused_mlp_kernel(const float* __restrict__ obs,
                                 const float* __restrict__ b1,
                                 const float* __restrict__ b2,
                                 const float* __restrict__ Hb1,
                                 const float* __restrict__ HW2,
                                 const float* __restrict__ Hb2,
                                 const unsigned short* __restrict__ W1T,
                                 const unsigned short* __restrict__ W2T,
                                 const unsigned short* __restrict__ HW1T,
                                 float* __restrict__ out) {
    __shared__ unsigned short buf[BE * 512];   // 64 KB: obs(first half), h, feat
    __shared__ float gpart[BE * 36];           // 9 KB : g partials (pad 36)

    const int tid  = threadIdx.x;
    const int lane = tid & 63;
    const int wid  = tid >> 6;   // 0..15 : col group (32 cols each)
    const int l15  = lane & 15;
    const int lk   = lane >> 4;  // 0..3
    const int e0   = blockIdx.x * BE;
    const int ag   = blockIdx.y;

    const f32x4 fzero = {0.f, 0.f, 0.f, 0.f};

    // ------------- stage obs tile [64][256] bf16 swizzled -------------
    {
        const unsigned fbase = ((unsigned)e0 * 64u + (unsigned)ag) * 256u;
        #pragma unroll 1
        for (int g = 0; g < 2; ++g) {
            unsigned gi  = (unsigned)tid + 1024u * g;   // 2048 groups of 8 floats
            unsigned row = gi >> 5;                     // 0..63
            unsigned kg  = (gi & 31u) << 3;
            unsigned fidx = fbase + row * 16384u + kg;
            const float4* p = reinterpret_cast<const float4*>(obs + fidx);
            float4 v0 = p[0], v1 = p[1];
            uint4 w;
            w.x = cvt_pk_bf16(v0.x, v0.y);
            w.y = cvt_pk_bf16(v0.z, v0.w);
            w.z = cvt_pk_bf16(v1.x, v1.y);
            w.w = cvt_pk_bf16(v1.z, v1.w);
            unsigned byt = (row * 512u + kg * 2u) ^ ((row & 7u) << 4);
            *reinterpret_cast<uint4*>(&buf[byt >> 1]) = w;
        }
    }
    __syncthreads();

    // ---------------- GEMM1: h = relu(obs @ W1 + b1), K=256 ----------------
    f32x4 acc[4][2];   // [mi][ni]: thread = act-row mi*16+l15, cols wid*32+ni*16+lk*4..+3
    #pragma unroll
    for (int i = 0; i < 4; ++i)
        #pragma unroll
        for (int j = 0; j < 2; ++j) acc[i][j] = fzero;

    {
        const unsigned short* bbase = W1T + (size_t)(wid * 32 + l15) * 256 + lk * 8;
        #pragma unroll 1
        for (int ks = 0; ks < 8; ++ks) {
            bf16x8 bA = *reinterpret_cast<const bf16x8*>(bbase + ks * 32);
            bf16x8 bB = *reinterpret_cast<const bf16x8*>(bbase + 16 * 256 + ks * 32);
            const int kk = ks * 32 + lk * 8;
            #pragma unroll
            for (int mi = 0; mi < 4; ++mi) {
                int row = mi * 16 + l15;
                bf16x8 af = *reinterpret_cast<const bf16x8*>(&buf[((row * 512 + kk * 2) ^ ((row & 7) << 4)) >> 1]);
                acc[mi][0] = __builtin_amdgcn_mfma_f32_16x16x32_bf16(bA, af, acc[mi][0], 0, 0, 0);
                acc[mi][1] = __builtin_amdgcn_mfma_f32_16x16x32_bf16(bB, af, acc[mi][1], 0, 0, 0);
            }
        }
    }
    __syncthreads();   // all obs reads done -> safe to overwrite buf with h

    // epilogue: +b1, relu, packed b64 writes into buf ([64][512] swizzled)
    #pragma unroll
    for (int ni = 0; ni < 2; ++ni) {
        const int col0 = wid * 32 + ni * 16 + lk * 4;
        const float4 bias = *reinterpret_cast<const float4*>(b1 + col0);
        #pragma unroll
        for (int mi = 0; mi < 4; ++mi) {
            int row = mi * 16 + l15;
            float v0 = fmaxf(acc[mi][ni][0] + bias.x, 0.f);
            float v1 = fmaxf(acc[mi][ni][1] + bias.y, 0.f);
            float v2 = fmaxf(acc[mi][ni][2] + bias.z, 0.f);
            float v3 = fmaxf(acc[mi][ni][3] + bias.w, 0.f);
            uint2 w = { cvt_pk_bf16(v0, v1), cvt_pk_bf16(v2, v3) };
            int byt = (row * 1024 + col0 * 2) ^ ((row & 7) << 4);
            *reinterpret_cast<uint2*>(&buf[byt >> 1]) = w;
        }
    }
    __syncthreads();

    // ---------------- GEMM2: feat = relu(h @ W2 + b2), K=512 ----------------
    #pragma unroll
    for (int i = 0; i < 4; ++i)
        #pragma unroll
        for (int j = 0; j < 2; ++j) acc[i][j] = fzero;

    {
        const unsigned short* bbase = W2T + (size_t)(wid * 32 + l15) * 512 + lk * 8;
        #pragma unroll 1
        for (int ks = 0; ks < 16; ++ks) {
            bf16x8 bA = *reinterpret_cast<const bf16x8*>(bbase + ks * 32);
            bf16x8 bB = *reinterpret_cast<const bf16x8*>(bbase + 16 * 512 + ks * 32);
            const int kk = ks * 32 + lk * 8;
            #pragma unroll
            for (int mi = 0; mi < 4; ++mi) {
                int row = mi * 16 + l15;
                bf16x8 af = *reinterpret_cast<const bf16x8*>(&buf[((row * 1024 + kk * 2) ^ ((row & 7) << 4)) >> 1]);
                acc[mi][0] = __builtin_amdgcn_mfma_f32_16x16x32_bf16(bA, af, acc[mi][0], 0, 0, 0);
                acc[mi][1] = __builtin_amdgcn_mfma_f32_16x16x32_bf16(bB, af, acc[mi][1], 0, 0, 0);
            }
        }
    }
    __syncthreads();   // all h reads done -> safe to overwrite buf with feat

    // epilogue: +b2, relu, packed b64 writes into buf ([64][512] swizzled)
    #pragma unroll
    for (int ni = 0; ni < 2; ++ni) {
        const int col0 = wid * 32 + ni * 16 + lk * 4;
        const float4 bias = *reinterpret_cast<const float4*>(b2 + col0);
        #pragma unroll
        for (int mi = 0; mi < 4; ++mi) {
            int row = mi * 16 + l15;
            float v0 = fmaxf(acc[mi][ni][0] + bias.x, 0.f);
            float v1 = fmaxf(acc[mi][ni][1] + bias.y, 0.f);
            float v2 = fmaxf(acc[mi][ni][2] + bias.z, 0.f);
            float v3 = fmaxf(acc[mi][ni][3] + bias.w, 0.f);
            uint2 w = { cvt_pk_bf16(v0, v1), cvt_pk_bf16(v2, v3) };
            int byt = (row * 1024 + col0 * 2) ^ ((row & 7) << 4);
            *reinterpret_cast<uint2*>(&buf[byt >> 1]) = w;
        }
    }
    __syncthreads();

    // ---------------- head1: g = relu(feat @ HW1[ag] + Hb1[ag]), N=32 ----------------
    // 16 waves: 4 row-quarters x 2 col-halves x 2 K-halves; gpart K-reduce.
    {
        const int hk  = wid >> 3;             // K half 0..1
        const int hm  = (wid >> 1) & 3;       // row quarter 0..3
        const int hc  = wid & 1;              // col half 0..1
        const int a32 = (ag << 5);
        const unsigned short* hbase = HW1T + (size_t)(a32 + hc * 16 + l15) * 512 + hk * 256 + lk * 8;
        f32x4 hacc = fzero;
        #pragma unroll 1
        for (int ks = 0; ks < 8; ++ks) {
            bf16x8 hb = *reinterpret_cast<const bf16x8*>(hbase + ks * 32);
            const int kk = hk * 256 + ks * 32 + lk * 8;
            int row = hm * 16 + l15;
            int byt = (row * 1024 + kk * 2) ^ ((row & 7) << 4);
            bf16x8 afh = *reinterpret_cast<const bf16x8*>(&buf[byt >> 1]);
            hacc = __builtin_amdgcn_mfma_f32_16x16x32_bf16(hb, afh, hacc, 0, 0, 0);
        }
        // transposed frag: thread owns feat-row hm*16+l15, cols hc*16+lk*4+0..3
        const int col0 = hc * 16 + lk * 4;
        const int row  = hm * 16 + l15;
        if (hk == 0) {
            const float4 hbias = *reinterpret_cast<const float4*>(Hb1 + a32 + col0);
            float4 g;
            g.x = hacc[0] + hbias.x;
            g.y = hacc[1] + hbias.y;
            g.z = hacc[2] + hbias.z;
            g.w = hacc[3] + hbias.w;
            *reinterpret_cast<float4*>(&gpart[row * 36 + col0]) = g;
        }
        __syncthreads();
        if (hk == 1) {
            float4 g = *reinterpret_cast<const float4*>(&gpart[row * 36 + col0]);
            g.x = fmaxf(g.x + hacc[0], 0.f);
            g.y = fmaxf(g.y + hacc[1], 0.f);
            g.z = fmaxf(g.z + hacc[2], 0.f);
            g.w = fmaxf(g.w + hacc[3], 0.f);
            *reinterpret_cast<float4*>(&gpart[row * 36 + col0]) = g;
        }
        __syncthreads();
    }

    // ---------------- head2: out = sigmoid(g . HW2[ag] + Hb2[ag]) ----------------
    if (tid < BE) {
        float x = Hb2[ag];
        #pragma unroll 2
        for (int k = 0; k < 32; ++k)
            x += gpart[tid * 36 + k] * HW2[(ag << 5) + k];
        out[(size_t)(e0 + tid) * N_AGENTS + ag] = 1.f / (1.f + expf(-x));
    }
}

extern "C" void kernel_launch(void* const* d_in, const int* in_sizes, int n_in,
                              void* d_out, int out_size, void* d_ws, size_t ws_size,
                              hipStream_t stream) {
    const float* obs = (const float*)d_in[0];
    const float* W1  = (const float*)d_in[1];
    const float* b1  = (const float*)d_in[2];
    const float* W2  = (const float*)d_in[3];
    const float* b2  = (const float*)d_in[4];
    const float* HW1 = (const float*)d_in[5];
    const float* Hb1 = (const float*)d_in[6];
    const float* HW2 = (const float*)d_in[7];
    const float* Hb2 = (const float*)d_in[8];
    float* out = (float*)d_out;

    unsigned short* W1T  = (unsigned short*)d_ws;     // 131072 elems
    unsigned short* W2T  = W1T + 131072;              // 262144 elems
    unsigned short* HW1T = W2T + 262144;              // 1048576 elems

    prep_weights_kernel<<<5632, 256, 0, stream>>>(W1, W2, HW1, W1T, W2T, HW1T);

    dim3 grid(N_ENVS / BE, N_AGENTS);
    fused_mlp_kernel<<<grid, 1024, 0, stream>>>(obs, b1, b2, Hb1, HW2, Hb2,
                                                W1T, W2T, HW1T, out);
}

// Round 15
// 323.655 us; speedup vs baseline: 1.4989x; 1.3656x over previous
//
#include <hip/hip_runtime.h>
#include <hip/hip_bf16.h>
#include <math.h>

#define N_ENVS   4096
#define N_AGENTS 64
#define OBS_DIM  256
#define HIDDEN   512
#define HEADK    32
#define BROWS    128   // rows per block = 64 envs x 2 agents

typedef __attribute__((ext_vector_type(8))) short bf16x8;
typedef __attribute__((ext_vector_type(4))) float f32x4;

// HW packed f32x2 -> bf16x2 (RNE). One VALU op replaces ~8 for two elements.
static __device__ __forceinline__ unsigned cvt_pk_bf16(float lo, float hi) {
    unsigned r;
    asm("v_cvt_pk_bf16_f32 %0, %1, %2" : "=v"(r) : "v"(lo), "v"(hi));
    return r;
}

static __device__ __forceinline__ unsigned short f2bf(float x) {
    union { float f; unsigned int u; } v; v.f = x;
    unsigned int r = (v.u + 0x7FFFu + ((v.u >> 16) & 1u)) >> 16;
    return (unsigned short)r;
}

// Convert + transpose weights to bf16, N-major (so B-fragments are 16B contiguous).
__global__ void prep_weights_kernel(const float* __restrict__ W1,
                                    const float* __restrict__ W2,
                                    const float* __restrict__ HW1,
                                    unsigned short* __restrict__ W1T,
                                    unsigned short* __restrict__ W2T,
                                    unsigned short* __restrict__ HW1T) {
    int id = blockIdx.x * 256 + threadIdx.x;
    if (id < 131072) {                      // W1 [256][512] -> W1T [512][256]
        int k = id >> 9, n = id & 511;
        W1T[n * 256 + k] = f2bf(W1[id]);
    } else if (id < 131072 + 262144) {      // W2 [512][512] -> W2T [512][512]
        int t = id - 131072;
        int k = t >> 9, n = t & 511;
        W2T[n * 512 + k] = f2bf(W2[t]);
    } else if (id < 131072 + 262144 + 1048576) {  // HW1 [64][512][32] -> HW1T [64][32][512]
        int t = id - (131072 + 262144);
        int ag = t >> 14;
        int rem = t & 16383;
        int hh = rem >> 5, c = rem & 31;
        HW1T[((ag << 5) + c) * 512 + hh] = f2bf(HW1[t]);
    }
}

// Fused MLP. EXACTLY the round-10 structure (best: 323us) + per-wave K-loop
// ROTATION. Round-14 killed the occupancy theory (90% occ, spill-free, still
// 442us): after each barrier all waves run the K-loop in LOCKSTEP -- identical
// progress means every wave hits its B-load-use stall (~250cy L2) at the same
// instant, so TLP cannot cover it and depth-1 prefetch (~80cy MFMA) is the
// only cover. Fix: wave w starts its (order-independent) K accumulation at
// step st(w) = (2w + (w>>2)) & mask -- distinct spread offsets for the 4
// waves per SIMD (wave->SIMD is i%4 round-robin) -> stalls de-phase and
// neighbors' MFMA clusters cover them. Correctness-neutral (fp32 acc
// reassociation only). Block = 128 rows (64 envs x 2 agents), 1024 thr =
// 16 waves x (128 rows x 32 cols), acc[8][2]=64 AGPR-side regs, depth-1 B
// prefetch, operand-swapped MFMA, transposed-frag packed epilogues.
__launch_bounds__(1024, 1)
__global__ void fused_mlp_kernel(const float* __restrict__ obs,
                                 const float* __restrict__ b1,
                                 const float* __restrict__ b2,
                                 const float* __restrict__ Hb1,
                                 const float* __restrict__ HW2,
                                 const float* __restrict__ Hb2,
                                 const unsigned short* __restrict__ W1T,
                                 const unsigned short* __restrict__ W2T,
                                 const unsigned short* __restrict__ HW1T,
                                 float* __restrict__ out) {
    __shared__ unsigned short buf[BROWS * 512];  // 128 KB: obs(first half), h, feat
    __shared__ float gpart[BROWS * 36];          // 18 KB : g (pad 36)

    const int tid  = threadIdx.x;
    const int lane = tid & 63;
    const int wid  = tid >> 6;   // 0..15 : col group (32 cols each)
    const int l15  = lane & 15;
    const int lk   = lane >> 4;  // 0..3
    const int e0   = blockIdx.x * 64;
    const int ap   = blockIdx.y; // agent pair: agents 2ap, 2ap+1
    const int stg  = 2 * wid + (wid >> 2);   // stagger seed (distinct mod 8/16 per SIMD)

    const f32x4 fzero = {0.f, 0.f, 0.f, 0.f};

    // ------------- stage obs tile [128][256] bf16 swizzled; row = j*64 + e -------------
    {
        const unsigned fbase = ((unsigned)e0 * 64u + 2u * (unsigned)ap) * 256u;
        #pragma unroll 1
        for (int g = 0; g < 4; ++g) {
            unsigned gi  = (unsigned)tid + 1024u * g;   // 4096 groups of 8 floats
            unsigned row = gi >> 5;                     // 0..127
            unsigned kg  = (gi & 31u) << 3;
            unsigned fidx = fbase + (row & 63u) * 16384u + (row >> 6) * 256u + kg;
            const float4* p = reinterpret_cast<const float4*>(obs + fidx);
            float4 v0 = p[0], v1 = p[1];
            uint4 w;
            w.x = cvt_pk_bf16(v0.x, v0.y);
            w.y = cvt_pk_bf16(v0.z, v0.w);
            w.z = cvt_pk_bf16(v1.x, v1.y);
            w.w = cvt_pk_bf16(v1.z, v1.w);
            unsigned byt = (row * 512u + kg * 2u) ^ ((row & 7u) << 4);
            *reinterpret_cast<uint4*>(&buf[byt >> 1]) = w;
        }
    }
    __syncthreads();

    // ---------------- GEMM1: h = relu(obs @ W1 + b1), K=256, staggered ----------------
    f32x4 acc[8][2];   // transposed frags: [mi][ni], thread = row mi*16+l15, cols ni*16+lk*4..+3
    #pragma unroll
    for (int i = 0; i < 8; ++i)
        #pragma unroll
        for (int j = 0; j < 2; ++j) acc[i][j] = fzero;

    {
        const int st = stg & 7;
        const unsigned short* bbase = W1T + (size_t)(wid * 32 + l15) * 256 + lk * 8;
        bf16x8 bcur[2];
        #pragma unroll
        for (int ni = 0; ni < 2; ++ni)
            bcur[ni] = *reinterpret_cast<const bf16x8*>(bbase + ni * 16 * 256 + st * 32);
        #pragma unroll 1
        for (int ks = 0; ks < 8; ++ks) {
            bf16x8 bnxt[2];
            const int kc = (st + ks) & 7;
            const int kn = (st + ks + 1) & 7;
            #pragma unroll
            for (int ni = 0; ni < 2; ++ni)
                bnxt[ni] = *reinterpret_cast<const bf16x8*>(bbase + ni * 16 * 256 + kn * 32);
            const int kk = kc * 32 + lk * 8;
            #pragma unroll
            for (int mi = 0; mi < 8; ++mi) {
                int row = mi * 16 + l15;
                bf16x8 af = *reinterpret_cast<const bf16x8*>(&buf[((row * 512 + kk * 2) ^ ((row & 7) << 4)) >> 1]);
                #pragma unroll
                for (int ni = 0; ni < 2; ++ni)
                    acc[mi][ni] = __builtin_amdgcn_mfma_f32_16x16x32_bf16(bcur[ni], af, acc[mi][ni], 0, 0, 0);
            }
            bcur[0] = bnxt[0]; bcur[1] = bnxt[1];
        }
    }
    __syncthreads();   // all obs reads done -> safe to overwrite buf with h

    // epilogue: +b1, relu, packed b64 writes into buf ([128][512] swizzled)
    #pragma unroll
    for (int ni = 0; ni < 2; ++ni) {
        const int col0 = wid * 32 + ni * 16 + lk * 4;
        const float4 bias = *reinterpret_cast<const float4*>(b1 + col0);
        #pragma unroll
        for (int mi = 0; mi < 8; ++mi) {
            int row = mi * 16 + l15;
            float v0 = fmaxf(acc[mi][ni][0] + bias.x, 0.f);
            float v1 = fmaxf(acc[mi][ni][1] + bias.y, 0.f);
            float v2 = fmaxf(acc[mi][ni][2] + bias.z, 0.f);
            float v3 = fmaxf(acc[mi][ni][3] + bias.w, 0.f);
            uint2 w = { cvt_pk_bf16(v0, v1), cvt_pk_bf16(v2, v3) };
            int byt = (row * 1024 + col0 * 2) ^ ((row & 7) << 4);
            *reinterpret_cast<uint2*>(&buf[byt >> 1]) = w;
        }
    }
    __syncthreads();

    // ---------------- GEMM2: feat = relu(h @ W2 + b2), K=512, staggered ----------------
    #pragma unroll
    for (int i = 0; i < 8; ++i)
        #pragma unroll
        for (int j = 0; j < 2; ++j) acc[i][j] = fzero;

    {
        const int st = stg & 15;
        const unsigned short* bbase = W2T + (size_t)(wid * 32 + l15) * 512 + lk * 8;
        bf16x8 bcur[2];
        #pragma unroll
        for (int ni = 0; ni < 2; ++ni)
            bcur[ni] = *reinterpret_cast<const bf16x8*>(bbase + ni * 16 * 512 + st * 32);
        #pragma unroll 1
        for (int ks = 0; ks < 16; ++ks) {
            bf16x8 bnxt[2];
            const int kc = (st + ks) & 15;
            const int kn = (st + ks + 1) & 15;
            #pragma unroll
            for (int ni = 0; ni < 2; ++ni)
                bnxt[ni] = *reinterpret_cast<const bf16x8*>(bbase + ni * 16 * 512 + kn * 32);
            const int kk = kc * 32 + lk * 8;
            #pragma unroll
            for (int mi = 0; mi < 8; ++mi) {
                int row = mi * 16 + l15;
                bf16x8 af = *reinterpret_cast<const bf16x8*>(&buf[((row * 1024 + kk * 2) ^ ((row & 7) << 4)) >> 1]);
                #pragma unroll
                for (int ni = 0; ni < 2; ++ni)
                    acc[mi][ni] = __builtin_amdgcn_mfma_f32_16x16x32_bf16(bcur[ni], af, acc[mi][ni], 0, 0, 0);
            }
            bcur[0] = bnxt[0]; bcur[1] = bnxt[1];
        }
    }
    __syncthreads();   // all h reads done -> safe to overwrite buf with feat

    // epilogue: +b2, relu, packed b64 writes into buf ([128][512] swizzled)
    #pragma unroll
    for (int ni = 0; ni < 2; ++ni) {
        const int col0 = wid * 32 + ni * 16 + lk * 4;
        const float4 bias = *reinterpret_cast<const float4*>(b2 + col0);
        #pragma unroll
        for (int mi = 0; mi < 8; ++mi) {
            int row = mi * 16 + l15;
            float v0 = fmaxf(acc[mi][ni][0] + bias.x, 0.f);
            float v1 = fmaxf(acc[mi][ni][1] + bias.y, 0.f);
            float v2 = fmaxf(acc[mi][ni][2] + bias.z, 0.f);
            float v3 = fmaxf(acc[mi][ni][3] + bias.w, 0.f);
            uint2 w = { cvt_pk_bf16(v0, v1), cvt_pk_bf16(v2, v3) };
            int byt = (row * 1024 + col0 * 2) ^ ((row & 7) << 4);
            *reinterpret_cast<uint2*>(&buf[byt >> 1]) = w;
        }
    }
    __syncthreads();

    // ---------------- head1: g = relu(feat @ HW1[agent] + Hb1), N=32, staggered ----------------
    // 16 waves: per agent of the pair, 4 row-quarters x 2 col-halves, full K=512.
    {
        const int ja  = wid >> 3;             // agent within pair
        const int sub = wid & 7;
        const int hm  = sub >> 1;             // row quarter 0..3
        const int hc  = sub & 1;              // col half 0..1
        const int a32 = ((2 * ap + ja) << 5);
        const int st  = stg & 15;
        const unsigned short* hbase = HW1T + (size_t)(a32 + hc * 16 + l15) * 512 + lk * 8;
        f32x4 hacc = fzero;
        bf16x8 hb = *reinterpret_cast<const bf16x8*>(hbase + st * 32);
        #pragma unroll 1
        for (int ks = 0; ks < 16; ++ks) {
            const int kc = (st + ks) & 15;
            const int kn = (st + ks + 1) & 15;
            bf16x8 hn = *reinterpret_cast<const bf16x8*>(hbase + kn * 32);
            const int kk = kc * 32 + lk * 8;
            int row = ja * 64 + hm * 16 + l15;
            int byt = (row * 1024 + kk * 2) ^ ((row & 7) << 4);
            bf16x8 afh = *reinterpret_cast<const bf16x8*>(&buf[byt >> 1]);
            hacc = __builtin_amdgcn_mfma_f32_16x16x32_bf16(hb, afh, hacc, 0, 0, 0);
            hb = hn;
        }
        // transposed frag: thread owns feat-row ja*64+hm*16+l15, cols hc*16+lk*4+0..3
        const int col0 = hc * 16 + lk * 4;
        const float4 hbias = *reinterpret_cast<const float4*>(Hb1 + a32 + col0);
        int row = ja * 64 + hm * 16 + l15;
        float4 g;
        g.x = fmaxf(hacc[0] + hbias.x, 0.f);
        g.y = fmaxf(hacc[1] + hbias.y, 0.f);
        g.z = fmaxf(hacc[2] + hbias.z, 0.f);
        g.w = fmaxf(hacc[3] + hbias.w, 0.f);
        *reinterpret_cast<float4*>(&gpart[row * 36 + col0]) = g;
    }
    __syncthreads();

    // ---------------- head2: out = sigmoid(g . HW2[agent] + Hb2) ----------------
    if (tid < BROWS) {
        int e = tid & 63, j = tid >> 6;
        int a = 2 * ap + j;
        float x = Hb2[a];
        #pragma unroll 2
        for (int k = 0; k < 32; ++k)
            x += gpart[tid * 36 + k] * HW2[(a << 5) + k];
        out[(size_t)(e0 + e) * N_AGENTS + a] = 1.f / (1.f + expf(-x));
    }
}

extern "C" void kernel_launch(void* const* d_in, const int* in_sizes, int n_in,
                              void* d_out, int out_size, void* d_ws, size_t ws_size,
                              hipStream_t stream) {
    const float* obs = (const float*)d_in[0];
    const float* W1  = (const float*)d_in[1];
    const float* b1  = (const float*)d_in[2];
    const float* W2  = (const float*)d_in[3];
    const float* b2  = (const float*)d_in[4];
    const float* HW1 = (const float*)d_in[5];
    const float* Hb1 = (const float*)d_in[6];
    const float* HW2 = (const float*)d_in[7];
    const float* Hb2 = (const float*)d_in[8];
    float* out = (float*)d_out;

    unsigned short* W1T  = (unsigned short*)d_ws;     // 131072 elems
    unsigned short* W2T  = W1T + 131072;              // 262144 elems
    unsigned short* HW1T = W2T + 262144;              // 1048576 elems

    prep_weights_kernel<<<5632, 256, 0, stream>>>(W1, W2, HW1, W1T, W2T, HW1T);

    dim3 grid(N_ENVS / 64, N_AGENTS / 2);
    fused_mlp_kernel<<<grid, 1024, 0, stream>>>(obs, b1, b2, Hb1, HW2, Hb2,
                                                W1T, W2T, HW1T, out);
}